// Round 12
// baseline (878.497 us; speedup 1.0000x reference)
//
#include <hip/hip_runtime.h>
#include <hip/hip_bf16.h>

// Problem: out[M=4096][N=16384] = x[M][K=4096] @ (W[N][K] * scale[N/128][K/128])^T + bias[N]
#define M_DIM 4096
#define N_DIM 16384
#define K_DIM 4096

typedef __bf16 bf16x8 __attribute__((ext_vector_type(8)));
typedef float f32x4 __attribute__((ext_vector_type(4)));

__device__ __forceinline__ void gload16(const void* g, void* l) {
    __builtin_amdgcn_global_load_lds((__attribute__((address_space(1))) void*)g,
                                     (__attribute__((address_space(3))) void*)l, 16, 0, 0);
}

// ---------- prepass 1: x fp32 -> bf16 ----------
__global__ __launch_bounds__(256) void cvt_x_kernel(const float* __restrict__ x,
                                                    __hip_bfloat16* __restrict__ out,
                                                    int ngroups) {
    int i = blockIdx.x * blockDim.x + threadIdx.x;
    int stride = gridDim.x * blockDim.x;
    for (; i < ngroups; i += stride) {
        const float4* p = (const float4*)(x + (size_t)i * 8);
        float4 v0 = p[0];
        float4 v1 = p[1];
        bf16x8 r;
        r[0] = (__bf16)v0.x; r[1] = (__bf16)v0.y; r[2] = (__bf16)v0.z; r[3] = (__bf16)v0.w;
        r[4] = (__bf16)v1.x; r[5] = (__bf16)v1.y; r[6] = (__bf16)v1.z; r[7] = (__bf16)v1.w;
        *(bf16x8*)(out + (size_t)i * 8) = r;
    }
}

// ---------- prepass 2: W fp32 * blockscale -> bf16 ----------
__global__ __launch_bounds__(256) void dequant_w_kernel(const float* __restrict__ w,
                                                        const float* __restrict__ scale,
                                                        __hip_bfloat16* __restrict__ out) {
    const int ngroups = N_DIM * (K_DIM / 8);
    int i = blockIdx.x * blockDim.x + threadIdx.x;
    int stride = gridDim.x * blockDim.x;
    for (; i < ngroups; i += stride) {
        int row = i >> 9;
        int cg  = i & 511;
        float s = scale[(row >> 7) * (K_DIM / 128) + (cg >> 4)];
        const float4* p = (const float4*)(w + (size_t)i * 8);
        float4 v0 = p[0];
        float4 v1 = p[1];
        bf16x8 r;
        r[0] = (__bf16)(v0.x * s); r[1] = (__bf16)(v0.y * s);
        r[2] = (__bf16)(v0.z * s); r[3] = (__bf16)(v0.w * s);
        r[4] = (__bf16)(v1.x * s); r[5] = (__bf16)(v1.y * s);
        r[6] = (__bf16)(v1.z * s); r[7] = (__bf16)(v1.w * s);
        *(bf16x8*)(out + (size_t)i * 8) = r;
    }
}

// ---------- main GEMM: 128x128 tile, BK=32, 4 waves, ~4 blocks/CU -----------
// r5-r11 post-mortem: 256^2/1-block-per-CU forces all 8 waves of a CU onto the
// SAME barriers -> read-burst / MFMA-burst alternation, pipes serialized at
// ~6000 cyc/K-tile regardless of schedule. Fix = OCCUPANCY: 32 KiB LDS +
// <=128 VGPR -> ~4 independent blocks/CU whose barriers interleave (m97/m114
// mechanism). Free-zone per K-step, structural sync only:
//   vmcnt(4|0); BAR;   [8 ds_read + 16 MFMA, compiler-scheduled]
//   lgkm0; BAR;  stage(kt+2)->buf[cur] (4 gloads/thread)
// vmcnt(4): queue = stage(kt) + stage(kt+1) (4 each, in-order) -> retires
// stage(kt) exactly. Stage slack = one full K-step + other blocks' work.
// Swizzle (rule #21, 64-B rows): stored slot s holds global slot
// s ^ ((row>>1)&3); stage-side scol = ((l&3)^((l>>3)&3))<<3; read-side
// col = (lk*8) ^ (((lr>>1)&3)<<3). Lanes spread 2-way max (free, m136).
template <int WN, bool ST>
__device__ __forceinline__ void ktile(const __hip_bfloat16* __restrict__ pa,
                                      const __hip_bfloat16* __restrict__ pb,
                                      char* lA, char* lB,
                                      const __hip_bfloat16* __restrict__ gA2,
                                      const __hip_bfloat16* __restrict__ gB2,
                                      f32x4 (&acc)[4][4],
                                      int aoff, int boff, int sr) {
    const size_t K = K_DIM;
    if (WN == 0) asm volatile("s_waitcnt vmcnt(0)" ::: "memory");
    else         asm volatile("s_waitcnt vmcnt(4)" ::: "memory");
    __builtin_amdgcn_s_barrier();

    // free zone: compiler schedules reads <-> MFMAs
    bf16x8 a[4], b[4];
    #pragma unroll
    for (int mi = 0; mi < 4; ++mi)
        a[mi] = *(const bf16x8*)(pa + aoff + mi * 512);
    #pragma unroll
    for (int ni = 0; ni < 4; ++ni)
        b[ni] = *(const bf16x8*)(pb + boff + ni * 512);
    #pragma unroll
    for (int mi = 0; mi < 4; ++mi)
        #pragma unroll
        for (int ni = 0; ni < 4; ++ni)
            acc[mi][ni] = __builtin_amdgcn_mfma_f32_16x16x32_bf16(
                a[mi], b[ni], acc[mi][ni], 0, 0, 0);

    asm volatile("s_waitcnt lgkmcnt(0)" ::: "memory");
    __builtin_amdgcn_s_barrier();
    if (ST) {
        gload16(gA2 + (size_t)sr * K,        lA);
        gload16(gA2 + (size_t)(64 + sr) * K, lA + 4096);
        gload16(gB2 + (size_t)sr * K,        lB);
        gload16(gB2 + (size_t)(64 + sr) * K, lB + 4096);
    }
}

__global__ __launch_bounds__(256, 4)
void gemm_bf16_kernel(const __hip_bfloat16* __restrict__ A,   // [M][K] bf16
                      const __hip_bfloat16* __restrict__ Bw,  // [N][K] bf16
                      const float* __restrict__ bias,
                      float* __restrict__ C) {                // [M][N] fp32
    constexpr int Mtiles = M_DIM / 128;            // 32
    constexpr int Ntiles = N_DIM / 128;            // 128
    constexpr int nwg = Mtiles * Ntiles;           // 4096 (div by 8)
    constexpr int NT = K_DIM / 32;                 // 128 K-steps

    int bid = blockIdx.x;
    int swz = (bid & 7) * (nwg >> 3) + (bid >> 3);   // bijective XCD swizzle
    int bm = swz % Mtiles;
    int bn = swz / Mtiles;

    __shared__ __align__(16) __hip_bfloat16 sA[2][128 * 32];   // 8 KiB each
    __shared__ __align__(16) __hip_bfloat16 sB[2][128 * 32];   // total 32 KiB

    const int t = threadIdx.x;
    const int l = t & 63;
    const int w = t >> 6;        // wave 0..3
    const int wm = w >> 1;       // 0..1
    const int wn = w & 1;        // 0..1

    const int lr = l & 15;
    const int lk = l >> 4;       // k-slot 0..3 (8 elems each)
    const int rx = ((lr >> 1) & 3) << 3;   // read-side element-col XOR

    // staging (rule #21): linear LDS dest; pre-swizzled global source col.
    // thread t -> LDS row (j*64 + w*16 + (l>>2)), slot (l&3).
    const int sr   = w * 16 + (l >> 2);
    const int scol = ((l & 3) ^ ((l >> 3) & 3)) << 3;

    const size_t K = K_DIM;
    const __hip_bfloat16* aB = A  + (size_t)(bm * 128) * K + scol;
    const __hip_bfloat16* bB = Bw + (size_t)(bn * 128) * K + scol;

    f32x4 acc[4][4] = {};

    const int aoff = (wm * 64 + lr) * 32 + ((lk * 8) ^ rx);
    const int boff = (wn * 64 + lr) * 32 + ((lk * 8) ^ rx);

    char* A0b = (char*)&sA[0][0] + w * 1024;
    char* B0b = (char*)&sB[0][0] + w * 1024;
    char* A1b = (char*)&sA[1][0] + w * 1024;
    char* B1b = (char*)&sB[1][0] + w * 1024;
    const __hip_bfloat16* pa0 = &sA[0][0];
    const __hip_bfloat16* pb0 = &sB[0][0];
    const __hip_bfloat16* pa1 = &sA[1][0];
    const __hip_bfloat16* pb1 = &sB[1][0];

#define STAGE4(lA, lB, gA, gB)                                                  \
    do {                                                                        \
        gload16((gA) + (size_t)sr * K,        (lA));                            \
        gload16((gA) + (size_t)(64 + sr) * K, (lA) + 4096);                     \
        gload16((gB) + (size_t)sr * K,        (lB));                            \
        gload16((gB) + (size_t)(64 + sr) * K, (lB) + 4096);                     \
    } while (0)

    // prologue: stage step0 -> buf0, step1 -> buf1 (8 gloads in flight)
    STAGE4(A0b, B0b, aB, bB);
    STAGE4(A1b, B1b, aB + 32, bB + 32);

    #pragma unroll 1
    for (int p = 0; p < 63; ++p) {
        const int kt = 2 * p;
        ktile<4, true>(pa0, pb0, A0b, B0b,
                       aB + (size_t)(kt + 2) * 32, bB + (size_t)(kt + 2) * 32,
                       acc, aoff, boff, sr);
        ktile<4, true>(pa1, pb1, A1b, B1b,
                       aB + (size_t)(kt + 3) * 32, bB + (size_t)(kt + 3) * 32,
                       acc, aoff, boff, sr);
    }
    // steps 126, 127: no further staging
    ktile<4, false>(pa0, pb0, A0b, B0b, aB, bB, acc, aoff, boff, sr);
    ktile<0, false>(pa1, pb1, A1b, B1b, aB, bB, acc, aoff, boff, sr);
#undef STAGE4

    // epilogue: C/D layout col=lane&15, row=(lane>>4)*4+reg  [m89-verified]
    const int crow0 = bm * 128 + wm * 64;
    const int ccol0 = bn * 128 + wn * 64;
    #pragma unroll
    for (int ni = 0; ni < 4; ++ni) {
        int col = ccol0 + ni * 16 + lr;
        float bv = bias[col];
        #pragma unroll
        for (int mi = 0; mi < 4; ++mi) {
            int rbase = crow0 + mi * 16 + lk * 4;
            #pragma unroll
            for (int j = 0; j < 4; ++j) {
                C[(size_t)(rbase + j) * N_DIM + col] = acc[mi][ni][j] + bv;
            }
        }
    }
}

// ---------- fallback (ws too small): fp32 LDS-tiled, correct but slow ----------
__global__ __launch_bounds__(256)
void gemm_fallback(const float* __restrict__ X, const float* __restrict__ W,
                   const float* __restrict__ scale, const float* __restrict__ bias,
                   float* __restrict__ C) {
    int bm = blockIdx.x % (M_DIM / 64);
    int bn = blockIdx.x / (M_DIM / 64);
    __shared__ float sA[64][33];
    __shared__ float sB[64][33];
    int t = threadIdx.x;
    int tx = t & 15, ty = t >> 4;
    float acc[4][4] = {};
    for (int kt = 0; kt < K_DIM / 32; ++kt) {
        float s = scale[(bn >> 1) * (K_DIM / 128) + (kt >> 2)];
        #pragma unroll
        for (int i = 0; i < 8; ++i) {
            int idx = t + i * 256;
            int r = idx >> 5, c = idx & 31;
            sA[r][c] = X[(size_t)(bm * 64 + r) * K_DIM + kt * 32 + c];
            sB[r][c] = W[(size_t)(bn * 64 + r) * K_DIM + kt * 32 + c] * s;
        }
        __syncthreads();
        #pragma unroll
        for (int k = 0; k < 32; ++k) {
            float a[4], b[4];
            #pragma unroll
            for (int i = 0; i < 4; ++i) a[i] = sA[ty * 4 + i][k];
            #pragma unroll
            for (int j = 0; j < 4; ++j) b[j] = sB[tx * 4 + j][k];
            #pragma unroll
            for (int i = 0; i < 4; ++i)
                #pragma unroll
                for (int j = 0; j < 4; ++j) acc[i][j] += a[i] * b[j];
        }
        __syncthreads();
    }
    #pragma unroll
    for (int i = 0; i < 4; ++i)
        #pragma unroll
        for (int j = 0; j < 4; ++j) {
            int row = bm * 64 + ty * 4 + i;
            int col = bn * 64 + tx * 4 + j;
            C[(size_t)row * N_DIM + col] = acc[i][j] + bias[col];
        }
}

extern "C" void kernel_launch(void* const* d_in, const int* in_sizes, int n_in,
                              void* d_out, int out_size, void* d_ws, size_t ws_size,
                              hipStream_t stream) {
    const float* x     = (const float*)d_in[0];   // [2,2048,4096]
    const float* wgt   = (const float*)d_in[1];   // [16384,4096]
    const float* scale = (const float*)d_in[2];   // [128,32]
    const float* bias  = (const float*)d_in[3];   // [16384]
    float* out = (float*)d_out;                   // [2,2048,16384]

    const size_t need = ((size_t)M_DIM * K_DIM + (size_t)N_DIM * K_DIM) * sizeof(__hip_bfloat16);
    if (ws_size >= need) {
        __hip_bfloat16* xbf = (__hip_bfloat16*)d_ws;
        __hip_bfloat16* wbf = xbf + (size_t)M_DIM * K_DIM;
        cvt_x_kernel<<<2048, 256, 0, stream>>>(x, xbf, M_DIM * K_DIM / 8);
        dequant_w_kernel<<<4096, 256, 0, stream>>>(wgt, scale, wbf);
        gemm_bf16_kernel<<<(M_DIM / 128) * (N_DIM / 128), 256, 0, stream>>>(xbf, wbf, bias, out);
    } else {
        gemm_fallback<<<(M_DIM / 64) * (N_DIM / 64), 256, 0, stream>>>(x, wgt, scale, bias, out);
    }
}

// Round 13
// 714.024 us; speedup vs baseline: 1.2303x; 1.2303x over previous
//
#include <hip/hip_runtime.h>
#include <hip/hip_bf16.h>

// Problem: out[M=4096][N=16384] = x[M][K=4096] @ (W[N][K] * scale[N/128][K/128])^T + bias[N]
#define M_DIM 4096
#define N_DIM 16384
#define K_DIM 4096

typedef __bf16 bf16x8 __attribute__((ext_vector_type(8)));
typedef float f32x4 __attribute__((ext_vector_type(4)));

__device__ __forceinline__ void gload16(const void* g, void* l) {
    __builtin_amdgcn_global_load_lds((__attribute__((address_space(1))) void*)g,
                                     (__attribute__((address_space(3))) void*)l, 16, 0, 0);
}

// ---------- prepass 1: x fp32 -> bf16 ----------
__global__ __launch_bounds__(256) void cvt_x_kernel(const float* __restrict__ x,
                                                    __hip_bfloat16* __restrict__ out,
                                                    int ngroups) {
    int i = blockIdx.x * blockDim.x + threadIdx.x;
    int stride = gridDim.x * blockDim.x;
    for (; i < ngroups; i += stride) {
        const float4* p = (const float4*)(x + (size_t)i * 8);
        float4 v0 = p[0];
        float4 v1 = p[1];
        bf16x8 r;
        r[0] = (__bf16)v0.x; r[1] = (__bf16)v0.y; r[2] = (__bf16)v0.z; r[3] = (__bf16)v0.w;
        r[4] = (__bf16)v1.x; r[5] = (__bf16)v1.y; r[6] = (__bf16)v1.z; r[7] = (__bf16)v1.w;
        *(bf16x8*)(out + (size_t)i * 8) = r;
    }
}

// ---------- prepass 2: W fp32 * blockscale -> bf16 ----------
__global__ __launch_bounds__(256) void dequant_w_kernel(const float* __restrict__ w,
                                                        const float* __restrict__ scale,
                                                        __hip_bfloat16* __restrict__ out) {
    const int ngroups = N_DIM * (K_DIM / 8);
    int i = blockIdx.x * blockDim.x + threadIdx.x;
    int stride = gridDim.x * blockDim.x;
    for (; i < ngroups; i += stride) {
        int row = i >> 9;
        int cg  = i & 511;
        float s = scale[(row >> 7) * (K_DIM / 128) + (cg >> 4)];
        const float4* p = (const float4*)(w + (size_t)i * 8);
        float4 v0 = p[0];
        float4 v1 = p[1];
        bf16x8 r;
        r[0] = (__bf16)(v0.x * s); r[1] = (__bf16)(v0.y * s);
        r[2] = (__bf16)(v0.z * s); r[3] = (__bf16)(v0.w * s);
        r[4] = (__bf16)(v1.x * s); r[5] = (__bf16)(v1.y * s);
        r[6] = (__bf16)(v1.z * s); r[7] = (__bf16)(v1.w * s);
        *(bf16x8*)(out + (size_t)i * 8) = r;
    }
}

// ---------- main GEMM: 256x256, BK=64, 8 waves, 8-phase (r9) + TYPED LDS -----
// Single change vs round 9: LDS tiles are declared as bf16x8 arrays and all
// fragment reads are native vector-element loads (slot index), guaranteeing
// ds_read_b128 emission. Previous rounds read via reinterpret-casts from a
// 2-byte-aligned pointee + XOR'd byte offsets — if the compiler loses the
// 16B alignment proof it splits loads (b64/b32), 2-8x LDS instr count, which
// matches the 6000-vs-3300 cyc/K-tile gap seen across r3-r11.
// Layout: row r (0..255) occupies slots [r*8, r*8+8); logical slot g of row r
// stored at slot g ^ (r&7) (rule #21: staged via pre-swizzled global col,
// LDS dest linear). Fragment rows are == lr (mod 8), so read slot =
// (s*4 + lk) ^ (lr&7). Schedule: identical to r9 (8-phase, 2 bars/phase,
// lgkm8 pre-bar on 12-read phases, vmcnt(4)@P4/P8, setprio, minimal fences).
__global__ __launch_bounds__(512, 2)
void gemm_bf16_kernel(const __hip_bfloat16* __restrict__ A,   // [M][K] bf16
                      const __hip_bfloat16* __restrict__ Bw,  // [N][K] bf16
                      const float* __restrict__ bias,
                      float* __restrict__ C) {                // [M][N] fp32
    constexpr int Mtiles = M_DIM / 256;            // 16
    constexpr int Ntiles = N_DIM / 256;            // 64
    constexpr int nwg = Mtiles * Ntiles;           // 1024 (div by 8)

    int bid = blockIdx.x;
    int swz = (bid & 7) * (nwg >> 3) + (bid >> 3);   // bijective XCD swizzle
    int bm = swz % Mtiles;
    int bn = swz / Mtiles;

    __shared__ bf16x8 sA[2][2048];   // 256 rows x 8 slots x 16B = 32 KiB each
    __shared__ bf16x8 sB[2][2048];   // total 128 KiB

    const int t = threadIdx.x;
    const int l = t & 63;
    const int w = t >> 6;        // wave 0..7
    const int wm = w >> 2;       // 0..1  (M half)
    const int wn = w & 3;        // 0..3  (N quarter)

    const int lr = l & 15;
    const int lk = l >> 4;
    const int l7 = lr & 7;

    // read slots: logical slot (s*4+lk) of row with row&7==l7
    const int s0 = lk ^ l7;            // k-half 0
    const int s1 = (4 + lk) ^ l7;      // k-half 1

    // staging (rule #21): linear LDS dest, pre-swizzled global source col.
    const int srow = w * 8 + (l >> 3);
    const int scol = ((l & 7) ^ (l >> 3)) << 3;

    const size_t K = K_DIM;
    const __hip_bfloat16* aB = A  + (size_t)(bm * 256) * K + scol;
    const __hip_bfloat16* bB = Bw + (size_t)(bn * 256) * K + scol;

    f32x4 acc[8][4] = {};

    const int arow = (wm * 128 + lr) * 8;   // slot base of A fragment rows
    const int brow = (wn * 64 + lr) * 8;    // slot base of B fragment rows

    char* A0b = (char*)&sA[0][0] + w * 1024;   // stage dest (+half*16384)
    char* B0b = (char*)&sB[0][0] + w * 1024;
    char* A1b = (char*)&sA[1][0] + w * 1024;
    char* B1b = (char*)&sB[1][0] + w * 1024;

// stage one half-tile (128 rows x 64 cols): 2 gloads/thread
#define SH(lbase, gptr)                                                         \
    do {                                                                        \
        gload16((gptr) + (size_t)srow * K, (lbase));                            \
        gload16((gptr) + (size_t)(64 + srow) * K, (lbase) + 8192);              \
    } while (0)

// a03/a47: 4 row-frags x 2 k-halves (8 slot-loads); b01/b23: 2 x 2 (4)
#define RD_A(dst, pa_, roff)                                                    \
    _Pragma("unroll")                                                           \
    for (int mi = 0; mi < 4; ++mi) {                                            \
        dst[mi][0] = (pa_)[arow + (roff) + mi * 128 + s0];                      \
        dst[mi][1] = (pa_)[arow + (roff) + mi * 128 + s1];                      \
    }

#define RD_B(dst, pb_, roff)                                                    \
    _Pragma("unroll")                                                           \
    for (int ni = 0; ni < 2; ++ni) {                                            \
        dst[ni][0] = (pb_)[brow + (roff) + ni * 128 + s0];                      \
        dst[ni][1] = (pb_)[brow + (roff) + ni * 128 + s1];                      \
    }

#define MM(mo, no, af, bf)                                                      \
    do {                                                                        \
        __builtin_amdgcn_s_setprio(1);                                          \
        _Pragma("unroll")                                                       \
        for (int s = 0; s < 2; ++s)                                             \
            _Pragma("unroll")                                                   \
            for (int mi = 0; mi < 4; ++mi)                                      \
                _Pragma("unroll")                                               \
                for (int ni = 0; ni < 2; ++ni)                                  \
                    acc[(mo) + mi][(no) + ni] =                                 \
                        __builtin_amdgcn_mfma_f32_16x16x32_bf16(                \
                            af[mi][s], bf[ni][s], acc[(mo) + mi][(no) + ni],    \
                            0, 0, 0);                                           \
        __builtin_amdgcn_s_setprio(0);                                          \
    } while (0)

#define BAR()   __builtin_amdgcn_s_barrier()
#define SBAR()  __builtin_amdgcn_sched_barrier(0)
#define LGKM0() do { asm volatile("s_waitcnt lgkmcnt(0)" ::: "memory"); SBAR(); } while (0)

    bf16x8 a03[4][2], a47[4][2], b01[2][2], b23[2][2];
    const bf16x8* pa0 = &sA[0][0];
    const bf16x8* pb0 = &sB[0][0];
    const bf16x8* pa1 = &sA[1][0];
    const bf16x8* pb1 = &sB[1][0];

    // prologue: tile0 full -> buf0; tile1 B halves -> buf1.B ; keep newest 4
    SH(A0b, aB);  SH(A0b + 16384, aB + (size_t)128 * K);
    SH(B0b, bB);  SH(B0b + 16384, bB + (size_t)128 * K);
    SH(B1b, bB + 64);  SH(B1b + 16384, bB + 64 + (size_t)128 * K);
    asm volatile("s_waitcnt vmcnt(4)" ::: "memory");   // tile0 resident
    BAR();

    #pragma unroll 1
    for (int p = 0; p < 32; ++p) {
        const bool last = (p == 31);
        const __hip_bfloat16* gAu  = aB + (size_t)(2 * p + 1) * 64;
        const __hip_bfloat16* gAt2 = aB + (size_t)(2 * p + 2) * 64;
        const __hip_bfloat16* gBt2 = bB + (size_t)(2 * p + 2) * 64;
        const __hip_bfloat16* gBt3 = bB + (size_t)(2 * p + 3) * 64;

        // ================= K-tile t = 2p (buf0) =================
        // --- P1: reads a03,b01 (12); stage buf1.A0<-u ---
        RD_A(a03, pa0, 0); RD_B(b01, pb0, 0);
        SH(A1b, gAu);
        asm volatile("s_waitcnt lgkmcnt(8)" ::: "memory");
        BAR();
        LGKM0();
        MM(0, 0, a03, b01);
        BAR();
        // --- P2: reads b23 (4); stage buf1.A1<-u ---
        RD_B(b23, pb0, 256);
        SH(A1b + 16384, gAu + (size_t)128 * K);
        BAR();
        LGKM0();
        MM(0, 2, a03, b23);
        BAR();
        // --- P3: reads a47 (8); stage buf0.B0<-t2 ---
        RD_A(a47, pa0, 512);
        if (!last) SH(B0b, gBt2);
        BAR();
        LGKM0();
        MM(4, 0, a47, b01);
        BAR();
        // --- P4: stage buf0.B1<-t2; vmcnt(4) -> buf1 resident ---
        if (!last) {
            SH(B0b + 16384, gBt2 + (size_t)128 * K);
            asm volatile("s_waitcnt vmcnt(4)" ::: "memory");
        } else {
            asm volatile("s_waitcnt vmcnt(0)" ::: "memory");
        }
        BAR();
        SBAR();
        MM(4, 2, a47, b23);
        BAR();

        // ================= K-tile u = 2p+1 (buf1) =================
        // --- P5: reads a03,b01 (12); stage buf0.A0<-t2 ---
        RD_A(a03, pa1, 0); RD_B(b01, pb1, 0);
        if (!last) SH(A0b, gAt2);
        asm volatile("s_waitcnt lgkmcnt(8)" ::: "memory");
        BAR();
        LGKM0();
        MM(0, 0, a03, b01);
        BAR();
        // --- P6: reads b23 (4); stage buf0.A1<-t2 ---
        RD_B(b23, pb1, 256);
        if (!last) SH(A0b + 16384, gAt2 + (size_t)128 * K);
        BAR();
        LGKM0();
        MM(0, 2, a03, b23);
        BAR();
        // --- P7: reads a47 (8); stage buf1.B0<-t3 ---
        RD_A(a47, pa1, 512);
        if (!last) SH(B1b, gBt3);
        BAR();
        LGKM0();
        MM(4, 0, a47, b01);
        BAR();
        // --- P8: stage buf1.B1<-t3; vmcnt(4) -> buf0 (t2) resident ---
        if (!last) {
            SH(B1b + 16384, gBt3 + (size_t)128 * K);
            asm volatile("s_waitcnt vmcnt(4)" ::: "memory");
        }
        BAR();
        SBAR();
        MM(4, 2, a47, b23);
        if (!last) BAR();
    }
#undef SH
#undef RD_A
#undef RD_B
#undef MM
#undef BAR
#undef SBAR
#undef LGKM0

    // epilogue: C/D layout col=lane&15, row=(lane>>4)*4+reg  [m89-verified]
    const int crow0 = bm * 256 + wm * 128;
    const int ccol0 = bn * 256 + wn * 64;
    #pragma unroll
    for (int ni = 0; ni < 4; ++ni) {
        int col = ccol0 + ni * 16 + lr;
        float bv = bias[col];
        #pragma unroll
        for (int mi = 0; mi < 8; ++mi) {
            int rbase = crow0 + mi * 16 + lk * 4;
            #pragma unroll
            for (int j = 0; j < 4; ++j) {
                C[(size_t)(rbase + j) * N_DIM + col] = acc[mi][ni][j] + bv;
            }
        }
    }
}

// ---------- fallback (ws too small): fp32 LDS-tiled, correct but slow ----------
__global__ __launch_bounds__(256)
void gemm_fallback(const float* __restrict__ X, const float* __restrict__ W,
                   const float* __restrict__ scale, const float* __restrict__ bias,
                   float* __restrict__ C) {
    int bm = blockIdx.x % (M_DIM / 64);
    int bn = blockIdx.x / (M_DIM / 64);
    __shared__ float sA[64][33];
    __shared__ float sB[64][33];
    int t = threadIdx.x;
    int tx = t & 15, ty = t >> 4;
    float acc[4][4] = {};
    for (int kt = 0; kt < K_DIM / 32; ++kt) {
        float s = scale[(bn >> 1) * (K_DIM / 128) + (kt >> 2)];
        #pragma unroll
        for (int i = 0; i < 8; ++i) {
            int idx = t + i * 256;
            int r = idx >> 5, c = idx & 31;
            sA[r][c] = X[(size_t)(bm * 64 + r) * K_DIM + kt * 32 + c];
            sB[r][c] = W[(size_t)(bn * 64 + r) * K_DIM + kt * 32 + c] * s;
        }
        __syncthreads();
        #pragma unroll
        for (int k = 0; k < 32; ++k) {
            float a[4], b[4];
            #pragma unroll
            for (int i = 0; i < 4; ++i) a[i] = sA[ty * 4 + i][k];
            #pragma unroll
            for (int j = 0; j < 4; ++j) b[j] = sB[tx * 4 + j][k];
            #pragma unroll
            for (int i = 0; i < 4; ++i)
                #pragma unroll
                for (int j = 0; j < 4; ++j) acc[i][j] += a[i] * b[j];
        }
        __syncthreads();
    }
    #pragma unroll
    for (int i = 0; i < 4; ++i)
        #pragma unroll
        for (int j = 0; j < 4; ++j) {
            int row = bm * 64 + ty * 4 + i;
            int col = bn * 64 + tx * 4 + j;
            C[(size_t)row * N_DIM + col] = acc[i][j] + bias[col];
        }
}

extern "C" void kernel_launch(void* const* d_in, const int* in_sizes, int n_in,
                              void* d_out, int out_size, void* d_ws, size_t ws_size,
                              hipStream_t stream) {
    const float* x     = (const float*)d_in[0];   // [2,2048,4096]
    const float* wgt   = (const float*)d_in[1];   // [16384,4096]
    const float* scale = (const float*)d_in[2];   // [128,32]
    const float* bias  = (const float*)d_in[3];   // [16384]
    float* out = (float*)d_out;                   // [2,2048,16384]

    const size_t need = ((size_t)M_DIM * K_DIM + (size_t)N_DIM * K_DIM) * sizeof(__hip_bfloat16);
    if (ws_size >= need) {
        __hip_bfloat16* xbf = (__hip_bfloat16*)d_ws;
        __hip_bfloat16* wbf = xbf + (size_t)M_DIM * K_DIM;
        cvt_x_kernel<<<2048, 256, 0, stream>>>(x, xbf, M_DIM * K_DIM / 8);
        dequant_w_kernel<<<4096, 256, 0, stream>>>(wgt, scale, wbf);
        gemm_bf16_kernel<<<(M_DIM / 256) * (N_DIM / 256), 512, 0, stream>>>(xbf, wbf, bias, out);
    } else {
        gemm_fallback<<<(M_DIM / 64) * (N_DIM / 64), 256, 0, stream>>>(x, wgt, scale, bias, out);
    }
}